// Round 8
// baseline (215.386 us; speedup 1.0000x reference)
//
#include <hip/hip_runtime.h>
#include <hip/hip_bf16.h>

// ExpertBank MoE FFN on gfx950 — round 17.
// r16 post-mortem: rider-transpose FAILED correctness (absmax 0.18, cause not isolated) ->
// full revert of W2T to k_prep fused branch (r13-r15 proven inline code). Kept insights:
// gemm2 = 256 blocks = 1/CU -> vmcnt+barrier drains fully exposed (same mechanism as r15's
// 1/CU regression); prep's routing block dispatched LAST = serial single-CU tail.
// r17: (1) gemm2 4-deep pipeline: 4 LDS buffers (128.5KB), 3 stages in flight, vmcnt(16)
// steady state, ONE barrier/K-step (top WAITN+BAR publishes stage kt AND protects buf kt&3
// from its kt+4 overwrite; intermediate bufs disjoint). ILP replaces missing TLP at 1/CU.
// (2) routing moved to block 0 of k_prep (overlaps bulk instead of tailing it).
// gemm1 = r14 exact. ws layout unchanged.
// ws: int[0..7] counts, [16..23] opad, [32..) rowmap(9216),
//     byte 65536: H bf16 [9216][2048] (37.75 MB), Xb bf16 (4.2 MB),
//     W1T bf16 (16.8 MB), [optional] W2T bf16 (16.8 MB).

typedef __bf16 bf16x8 __attribute__((ext_vector_type(8)));
typedef float f32x4 __attribute__((ext_vector_type(4)));

#define DM 512
#define DF 2048
#define NE 8
#define NTOK 4096
#define NPAIR 8192
#define HCAP 9216

__device__ __forceinline__ unsigned short f2bf(float x) {
    unsigned u = __builtin_bit_cast(unsigned, x);
    return (unsigned short)((u + 0x7fffu + ((u >> 16) & 1u)) >> 16);
}
__device__ __forceinline__ unsigned pack2(float lo, float hi) {
    return (unsigned)f2bf(lo) | ((unsigned)f2bf(hi) << 16);
}
// tanh-form GELU == x*sigmoid(2y); log2e folded: gelu = x * rcp(1 + exp2(z)). |err|~3e-4.
__device__ __forceinline__ float gelu_fast(float x) {
    float x2 = x * x;
    float z = x * __builtin_fmaf(x2, -0.1029432f, -2.3022083f);
    float e = __builtin_amdgcn_exp2f(z);
    return x * __builtin_amdgcn_rcpf(1.0f + e);
}
// async 16B global->LDS (gfx950); lds pointer must be wave-uniform, writes lane*16B
__device__ __forceinline__ void dma16(const unsigned short* g, unsigned short* l) {
    __builtin_amdgcn_global_load_lds(
        (const __attribute__((address_space(1))) void*)g,
        (__attribute__((address_space(3))) void*)l, 16, 0, 0);
}
// BK=64 tile [128][64] bf16: 8 16B-chunks per 128B row; XOR swizzle chunk^(row&7).
__device__ __forceinline__ int slot64(int row, int c) { return row * 8 + (c ^ (row & 7)); }

// one 128x128x64 MFMA step (2 x K=32 sub-steps) from swizzled LDS tiles
__device__ __forceinline__ void mfma_step(const unsigned short* Ab, const unsigned short* Bb,
                                          int wm, int wn, int quad, int l15,
                                          f32x4 (&acc)[4][4]) {
#pragma unroll
    for (int kk = 0; kk < 2; ++kk) {
        const int c = kk * 4 + quad;
        bf16x8 a[4], b[4];
#pragma unroll
        for (int fm = 0; fm < 4; ++fm) {
            int row = wm * 64 + fm * 16 + l15;
            a[fm] = __builtin_bit_cast(bf16x8, *(const uint4*)&Ab[slot64(row, c) * 8]);
        }
#pragma unroll
        for (int fn = 0; fn < 4; ++fn) {
            int row = wn * 64 + fn * 16 + l15;
            b[fn] = __builtin_bit_cast(bf16x8, *(const uint4*)&Bb[slot64(row, c) * 8]);
        }
#pragma unroll
        for (int fm = 0; fm < 4; ++fm)
#pragma unroll
            for (int fn = 0; fn < 4; ++fn)
                acc[fm][fn] = __builtin_amdgcn_mfma_f32_16x16x32_bf16(a[fm], b[fn], acc[fm][fn], 0, 0, 0);
    }
}

// 8 dma16 per wave per STAGE (4 A + 4 B); ko in ushort elements; buf stride 8192 ushorts
#define STAGE(buf, ko)                                        \
    do {                                                      \
        _Pragma("unroll") for (int j_ = 0; j_ < 4; ++j_) {    \
            dma16(ga[j_] + (ko), la[j_] + (buf) * 8192);      \
            dma16(gb[j_] + (ko), lb[j_] + (buf) * 8192);      \
        }                                                     \
    } while (0)

#define WAITN(n)                                                  \
    do {                                                          \
        __builtin_amdgcn_sched_barrier(0);                        \
        asm volatile("s_waitcnt vmcnt(" #n ")" ::: "memory");     \
        __builtin_amdgcn_sched_barrier(0);                        \
    } while (0)

#define BAR() __builtin_amdgcn_s_barrier()

// ---- mega-prep: 0 routing, [1,1025) cvtX, [1025,3073) tw(W1),
// ----            [3073,5121) tw(W2)  (only dispatched in fused mode) ----
__global__ void k_prep(const float* __restrict__ X, unsigned short* __restrict__ Xb,
                       const float* __restrict__ W1, unsigned short* __restrict__ W1T,
                       const float* __restrict__ W2, unsigned short* __restrict__ W2T,
                       const int* __restrict__ sel, int* __restrict__ counts_g,
                       int* __restrict__ opad_g, int* __restrict__ rowmap,
                       float* __restrict__ loads_out) {
    __shared__ unsigned short T[64][65];
    __shared__ int hist[NE], cur[NE], off[NE];
    const int b = blockIdx.x, tid = threadIdx.x;

    if (b == 0) {  // routing FIRST (block 0): histogram + padded scan + compact assign
        if (tid < NE) { hist[tid] = 0; cur[tid] = 0; }
        __syncthreads();
#pragma unroll
        for (int i = 0; i < NPAIR / 256; ++i)
            atomicAdd(&hist[sel[i * 256 + tid]], 1);
        __syncthreads();
        if (tid == 0) {
            int s = 0;
            for (int e = 0; e < NE; ++e) {
                off[e] = s;
                s += (hist[e] + 127) & ~127;
                counts_g[e] = hist[e];
                opad_g[e] = off[e];
                loads_out[e] = (float)hist[e] * (1.0f / (float)NTOK);
            }
        }
        __syncthreads();
#pragma unroll
        for (int i = 0; i < NPAIR / 256; ++i) {
            int p = i * 256 + tid;
            int e = sel[p];
            int pos = atomicAdd(&cur[e], 1);
            rowmap[off[e] + pos] = p;
        }
    } else if (b < 1025) {  // X fp32 -> bf16
        int i = ((b - 1) * 256 + tid) * 8;
        float4 a = *(const float4*)(X + i);
        float4 c = *(const float4*)(X + i + 4);
        uint4 u;
        u.x = pack2(a.x, a.y); u.y = pack2(a.z, a.w);
        u.z = pack2(c.x, c.y); u.w = pack2(c.z, c.w);
        *(uint4*)(Xb + i) = u;
    } else if (b < 3073) {  // W1 [E][DM][DF] -> bf16 W1T [E][DF][DM]
        const int t = b - 1025;
        const int bx = t & 31, by = (t >> 5) & 7, bz = t >> 8;
        const int tx = tid & 15, ty = tid >> 4;
        const int r0 = by * 64, c0 = bx * 64;
        const float* src = W1 + ((size_t)bz * DM + r0) * DF + c0;
#pragma unroll
        for (int i = 0; i < 4; ++i) {
            int r = ty + i * 16;
            float4 v = *(const float4*)(src + (size_t)r * DF + tx * 4);
            T[tx * 4 + 0][r] = f2bf(v.x); T[tx * 4 + 1][r] = f2bf(v.y);
            T[tx * 4 + 2][r] = f2bf(v.z); T[tx * 4 + 3][r] = f2bf(v.w);
        }
        __syncthreads();
        unsigned short* dst = W1T + ((size_t)bz * DF + c0) * DM + r0;
#pragma unroll
        for (int i = 0; i < 4; ++i) {
            int c = ty + i * 16;
            ushort4 w;
            w.x = T[c][tx * 4 + 0]; w.y = T[c][tx * 4 + 1];
            w.z = T[c][tx * 4 + 2]; w.w = T[c][tx * 4 + 3];
            *(ushort4*)(dst + (size_t)c * DM + tx * 4) = w;
        }
    } else {  // W2 [E][DF][DM] -> bf16 W2T [E][DM][DF] (fused mode only)
        const int t = b - 3073;
        const int bx = t & 7, by = (t >> 3) & 31, bz = t >> 8;
        const int tx = tid & 15, ty = tid >> 4;
        const int r0 = by * 64, c0 = bx * 64;
        const float* src = W2 + ((size_t)bz * DF + r0) * DM + c0;
#pragma unroll
        for (int i = 0; i < 4; ++i) {
            int r = ty + i * 16;
            float4 v = *(const float4*)(src + (size_t)r * DM + tx * 4);
            T[tx * 4 + 0][r] = f2bf(v.x); T[tx * 4 + 1][r] = f2bf(v.y);
            T[tx * 4 + 2][r] = f2bf(v.z); T[tx * 4 + 3][r] = f2bf(v.w);
        }
        __syncthreads();
        unsigned short* dst = W2T + ((size_t)bz * DM + c0) * DF + r0;
#pragma unroll
        for (int i = 0; i < 4; ++i) {
            int c = ty + i * 16;
            ushort4 w;
            w.x = T[c][tx * 4 + 0]; w.y = T[c][tx * 4 + 1];
            w.z = T[c][tx * 4 + 2]; w.w = T[c][tx * 4 + 3];
            *(ushort4*)(dst + (size_t)c * DF + tx * 4) = w;
        }
    }
}

// ---- W2 [E][DF][DM] -> bf16 W2T [E][DM][DF] (fallback when ws too small to fuse) ----
__global__ void k_tw2(const float* __restrict__ in, unsigned short* __restrict__ out) {
    __shared__ unsigned short T[64][65];
    const int tid = threadIdx.x;
    const int tx = tid & 15, ty = tid >> 4;
    const int r0 = blockIdx.y * 64, c0 = blockIdx.x * 64;
    const float* src = in + ((size_t)blockIdx.z * DF + r0) * DM + c0;
#pragma unroll
    for (int i = 0; i < 4; ++i) {
        int r = ty + i * 16;
        float4 v = *(const float4*)(src + (size_t)r * DM + tx * 4);
        T[tx * 4 + 0][r] = f2bf(v.x); T[tx * 4 + 1][r] = f2bf(v.y);
        T[tx * 4 + 2][r] = f2bf(v.z); T[tx * 4 + 3][r] = f2bf(v.w);
    }
    __syncthreads();
    unsigned short* dst = out + ((size_t)blockIdx.z * DM + c0) * DF + r0;
#pragma unroll
    for (int i = 0; i < 4; ++i) {
        int c = ty + i * 16;
        ushort4 w;
        w.x = T[c][tx * 4 + 0]; w.y = T[c][tx * 4 + 1];
        w.z = T[c][tx * 4 + 2]; w.w = T[c][tx * 4 + 3];
        *(ushort4*)(dst + (size_t)c * DF + tx * 4) = w;
    }
}

// ---------------- GEMM1: H = gelu(Xb[tok] @ W1), 128x128, BK=64, dbuf counted-vmcnt ----
// r14-exact. LDS: SM[0..1]=A dbuf, SM[2..3]=B dbuf; epilogue reuses SM as [128][136] C-tile.
__launch_bounds__(256, 2)
__global__ void k_gemm1d(const unsigned short* __restrict__ Xb,
                         const unsigned short* __restrict__ W1T,
                         const int* __restrict__ counts, const int* __restrict__ opad,
                         const int* __restrict__ rowmap, unsigned short* __restrict__ H) {
    const int e = blockIdx.z, mt = blockIdx.y, nt = blockIdx.x;
    const int grow = opad[e] + mt * 128;
    int valid = counts[e] - mt * 128;
    if (valid <= 0) return;
    if (valid > 128) valid = 128;

    __shared__ __align__(16) unsigned short SM[4][8192];
    __shared__ int toks[128];

    const int tid = threadIdx.x;
    if (tid < 128) {
        int i = (tid < valid) ? tid : 0;
        toks[tid] = rowmap[grow + i] >> 1;
    }
    __syncthreads();

    const int wave = tid >> 6, lane = tid & 63;
    const int wm = wave >> 1, wn = wave & 1;
    const int quad = lane >> 4, l15 = lane & 15;

    const unsigned short* ga[4];
    const unsigned short* gb[4];
    unsigned short* la[4];
    unsigned short* lb[4];
#pragma unroll
    for (int j = 0; j < 4; ++j) {
        int row = wave * 32 + j * 8 + (lane >> 3);
        int ch = (lane & 7) ^ ((lane >> 3) & 7);
        ga[j] = Xb + (size_t)toks[row] * DM + ch * 8;
        gb[j] = W1T + ((size_t)e * DF + nt * 128 + row) * DM + ch * 8;
        la[j] = &SM[0][(wave * 32 + j * 8) * 64];
        lb[j] = &SM[2][(wave * 32 + j * 8) * 64];
    }

    f32x4 acc[4][4] = {};

    STAGE(0, 0);
#pragma unroll 1
    for (int kt = 0; kt < 8; kt += 2) {
        if (kt + 1 < 8) { STAGE(1, (kt + 1) * 64); WAITN(8); } else { WAITN(0); }
        BAR();
        mfma_step(&SM[0][0], &SM[2][0], wm, wn, quad, l15, acc);
        BAR();
        if (kt + 2 < 8) { STAGE(0, (kt + 2) * 64); WAITN(8); } else { WAITN(0); }
        BAR();
        mfma_step(&SM[1][0], &SM[3][0], wm, wn, quad, l15, acc);
        BAR();
    }

    // ---- epilogue through LDS: bf16 C-tile [128][136], then coalesced 16B stores ----
    unsigned short* ep = &SM[0][0];
#pragma unroll
    for (int fm = 0; fm < 4; ++fm)
#pragma unroll
        for (int i = 0; i < 4; ++i) {
            int r = wm * 64 + fm * 16 + quad * 4 + i;
#pragma unroll
            for (int fn = 0; fn < 4; ++fn)
                ep[r * 136 + wn * 64 + fn * 16 + l15] = f2bf(gelu_fast(acc[fm][fn][i]));
        }
    __syncthreads();
    {
        const int rr0 = tid >> 4, ch = tid & 15;
#pragma unroll
        for (int it = 0; it < 8; ++it) {
            int r = it * 16 + rr0;
            uint4 v = *(const uint4*)&ep[r * 136 + ch * 8];
            *(uint4*)(H + (size_t)(grow + r) * DF + nt * 128 + ch * 8) = v;
        }
    }
}

// ------- GEMM2: out = H @ W2 (K=2048, plain stores), 128x128, 4-deep pipeline ----------
// 256 working blocks = 1/CU -> replace TLP with ILP: 4 LDS buffers, 3 stages in flight,
// vmcnt(16) steady state, ONE barrier per K-step (top WAITN+BAR publishes stage kt and
// protects buf kt&3 from its kt+4 overwrite; bufs kt+1..kt+3 are disjoint).
__launch_bounds__(256, 1)
__global__ void k_gemm2d(const unsigned short* __restrict__ H,
                         const unsigned short* __restrict__ W2T,
                         const int* __restrict__ counts, const int* __restrict__ opad,
                         const int* __restrict__ rowmap, float* __restrict__ out) {
    const int e = blockIdx.z, mt = blockIdx.y, nt = blockIdx.x;
    const int grow = opad[e] + mt * 128;
    int valid = counts[e] - mt * 128;
    if (valid <= 0) return;
    if (valid > 128) valid = 128;

    __shared__ __align__(16) unsigned short As[4][8192];   // 64 KB (A: 128x64 x4)
    __shared__ __align__(16) unsigned short Bs[4][8192];   // 64 KB (B: 128x64 x4)
    __shared__ int pairs[128];

    const int tid = threadIdx.x;
    if (tid < 128) pairs[tid] = (tid < valid) ? rowmap[grow + tid] : 0;
    __syncthreads();

    const int wave = tid >> 6, lane = tid & 63;
    const int wm = wave >> 1, wn = wave & 1;
    const int quad = lane >> 4, l15 = lane & 15;

    const unsigned short* ga[4];
    const unsigned short* gb[4];
    unsigned short* la[4];
    unsigned short* lb[4];
#pragma unroll
    for (int j = 0; j < 4; ++j) {
        int row = wave * 32 + j * 8 + (lane >> 3);
        int ch = (lane & 7) ^ ((lane >> 3) & 7);
        int rr = (row < valid) ? row : 0;  // clamp: never read unwritten H (r7 lesson)
        ga[j] = H + (size_t)(grow + rr) * DF + ch * 8;
        gb[j] = W2T + ((size_t)e * DM + nt * 128 + row) * DF + ch * 8;
        la[j] = &As[0][(wave * 32 + j * 8) * 64];
        lb[j] = &Bs[0][(wave * 32 + j * 8) * 64];
    }

    f32x4 acc[4][4] = {};

    STAGE(0, 0); STAGE(1, 64); STAGE(2, 128);  // 3 stages in flight (24 loads/wave)
#pragma unroll 1
    for (int kt = 0; kt < 32; ++kt) {
        if (kt < 30) { WAITN(16); }        // oldest stage (kt) complete, 2 stay in flight
        else if (kt == 30) { WAITN(8); }
        else { WAITN(0); }
        BAR();                              // all waves' stage-kt writes visible
        const int buf = kt & 3;
        mfma_step(&As[buf][0], &Bs[buf][0], wm, wn, quad, l15, acc);
        if (kt + 3 < 32) STAGE((kt + 3) & 3, (kt + 3) * 64);
    }

#pragma unroll
    for (int fm = 0; fm < 4; ++fm) {
#pragma unroll
        for (int i = 0; i < 4; ++i) {
            int m_l = wm * 64 + fm * 16 + quad * 4 + i;
            if (m_l < valid) {
                float* orow = out + (size_t)pairs[m_l] * DM + nt * 128 + wn * 64;
#pragma unroll
                for (int fn = 0; fn < 4; ++fn)
                    orow[fn * 16 + l15] = acc[fm][fn][i];  // exactly-once: plain store
            }
        }
    }
}

extern "C" void kernel_launch(void* const* d_in, const int* in_sizes, int n_in,
                              void* d_out, int out_size, void* d_ws, size_t ws_size,
                              hipStream_t stream) {
    const float* X = (const float*)d_in[0];
    const int* sel = (const int*)d_in[1];
    const float* W1 = (const float*)d_in[3];
    const float* W2 = (const float*)d_in[4];
    float* out = (float*)d_out;
    float* loads_out = out + (size_t)NPAIR * DM;

    int* counts = (int*)d_ws;
    int* opad = counts + 16;
    int* rowmap = counts + 32;
    const size_t hbytes = (size_t)HCAP * DF * 2;
    const size_t xbytes = (size_t)NTOK * DM * 2;
    const size_t w1tbytes = (size_t)NE * DF * DM * 2;
    unsigned short* H = (unsigned short*)((char*)d_ws + 65536);
    unsigned short* Xb = (unsigned short*)((char*)d_ws + 65536 + hbytes);
    unsigned short* WT = (unsigned short*)((char*)d_ws + 65536 + hbytes + xbytes);

    // fused mode: separate W2T buffer -> W2 transpose folds into k_prep, no k_tw2 dispatch
    const bool fused = ws_size >= 65536 + hbytes + xbytes + 2 * w1tbytes;
    unsigned short* W2T = fused ? WT + w1tbytes / 2 : WT;

    hipLaunchKernelGGL(k_prep, dim3(fused ? 5121 : 3073), dim3(256), 0, stream,
                       X, Xb, W1, WT, W2, W2T, sel, counts, opad, rowmap, loads_out);
    hipLaunchKernelGGL(k_gemm1d, dim3(DF / 128, NPAIR / 128, NE), dim3(256), 0, stream,
                       Xb, WT, counts, opad, rowmap, H);
    if (!fused)
        hipLaunchKernelGGL(k_tw2, dim3(DM / 64, DF / 64, NE), dim3(256), 0, stream, W2, WT);
    hipLaunchKernelGGL(k_gemm2d, dim3(4, NPAIR / 128, NE), dim3(256), 0, stream,
                       H, W2T, counts, opad, rowmap, out);
}